// Round 2
// baseline (198.699 us; speedup 1.0000x reference)
//
#include <hip/hip_runtime.h>

#define HH 256
#define WW 256
#define CC 32
#define HWSZ (HH * WW)
#define IMGSZ (CC * HWSZ)
#define NIMG 8
#define EPSV 1e-8f

// Load the 3x4 halo for one channel around this thread's 2 pixels.
// v[r][j] = F[c, y+r-1, x0-1+j], zero outside the image.
__device__ __forceinline__ void load_halo(const float* __restrict__ plane,
                                          bool ym, bool yp, bool xl, bool xr,
                                          float v[3][4])
{
    const bool rowok[3] = { ym, true, yp };
#pragma unroll
    for (int r = 0; r < 3; ++r) {
        const float* row = plane + (r - 1) * WW;
        if (rowok[r]) {
            float2 m = *reinterpret_cast<const float2*>(row);
            v[r][1] = m.x; v[r][2] = m.y;
            v[r][0] = xl ? row[-1] : 0.f;
            v[r][3] = xr ? row[2]  : 0.f;
        } else {
#pragma unroll
            for (int j = 0; j < 4; ++j) v[r][j] = 0.f;
        }
    }
}

__device__ __forceinline__ void acc_pass1(const float v[3][4],
                                          float sq[3][4], float dotv[8][2])
{
#pragma unroll
    for (int r = 0; r < 3; ++r)
#pragma unroll
        for (int j = 0; j < 4; ++j) sq[r][j] = fmaf(v[r][j], v[r][j], sq[r][j]);
    int d = 0;
#pragma unroll
    for (int dyi = 0; dyi < 3; ++dyi)
#pragma unroll
        for (int dxi = 0; dxi < 3; ++dxi) {
            if (dyi == 1 && dxi == 1) continue;
#pragma unroll
            for (int i = 0; i < 2; ++i)
                dotv[d][i] = fmaf(v[1][i + 1], v[dyi][i + dxi], dotv[d][i]);
            ++d;
        }
}

__device__ __forceinline__ void acc_pass2(const float v[3][4],
                                          const float w[8][2], float o[2])
{
    int d = 0;
#pragma unroll
    for (int dyi = 0; dyi < 3; ++dyi)
#pragma unroll
        for (int dxi = 0; dxi < 3; ++dxi) {
            if (dyi == 1 && dxi == 1) continue;
#pragma unroll
            for (int i = 0; i < 2; ++i)
                o[i] = fmaf(w[d][i], v[dyi][i + dxi], o[i]);
            ++d;
        }
}

// One "step": per image, write the total-sim map and, if COMPUTE_NEXT, the
// softmax-neighbor-averaged F_next. Each thread owns 2 horizontal pixels.
template <bool COMPUTE_NEXT>
__global__ __launch_bounds__(256) void step_kernel(const float* __restrict__ F,
                                                   float* __restrict__ Fn,
                                                   float* __restrict__ simout)
{
    const int tx = threadIdx.x & 127;  // 128 threads x 2 px = 256 px per row
    const int ty = threadIdx.x >> 7;   // 2 rows per block
    const int y  = (blockIdx.x << 1) + ty;
    const int b  = blockIdx.y;
    const int x0 = tx << 1;

    const float* Fb = F + (size_t)b * IMGSZ;
    const bool ym = y > 0, yp = y < HH - 1;
    const bool xl = x0 > 0, xr = x0 < WW - 2;
    const bool rowok[3] = { ym, true, yp };
    const bool colok[4] = { xl, true, true, xr };

    float sq[3][4];
    float dotv[8][2];
#pragma unroll
    for (int r = 0; r < 3; ++r)
#pragma unroll
        for (int j = 0; j < 4; ++j) sq[r][j] = 0.f;
#pragma unroll
    for (int d = 0; d < 8; ++d)
#pragma unroll
        for (int i = 0; i < 2; ++i) dotv[d][i] = 0.f;

    const float* base = Fb + y * WW + x0;

    // Pass 1: norms + neighbor dots, 2-deep software pipeline over channels.
    {
        float va[3][4], vb[3][4];
        load_halo(base, ym, yp, xl, xr, va);
        for (int c = 0; c < CC; c += 2) {
            load_halo(base + (c + 1) * HWSZ, ym, yp, xl, xr, vb);
            acc_pass1(va, sq, dotv);
            if (c + 2 < CC) load_halo(base + (c + 2) * HWSZ, ym, yp, xl, xr, va);
            acc_pass1(vb, sq, dotv);
        }
    }

    float nrm[3][4];
#pragma unroll
    for (int r = 0; r < 3; ++r)
#pragma unroll
        for (int j = 0; j < 4; ++j) nrm[r][j] = sqrtf(sq[r][j]);

    float w[8][2];
    float simarr[2];
#pragma unroll
    for (int i = 0; i < 2; ++i) {
        float s[8];
        const float cn = nrm[1][i + 1];
        float tot = 0.f, cnt = 0.f;
        int d = 0;
#pragma unroll
        for (int dyi = 0; dyi < 3; ++dyi)
#pragma unroll
            for (int dxi = 0; dxi < 3; ++dxi) {
                if (dyi == 1 && dxi == 1) continue;
                const bool m = rowok[dyi] && colok[i + dxi];
                const float den = fmaxf(cn * nrm[dyi][i + dxi], EPSV);
                const float cs = dotv[d][i] / den;
                s[d] = m ? cs : 0.f;
                tot += s[d];
                cnt += m ? 1.f : 0.f;
                ++d;
            }
        simarr[i] = tot / cnt;
        if (COMPUTE_NEXT) {
            float mx = s[0];
#pragma unroll
            for (int d2 = 1; d2 < 8; ++d2) mx = fmaxf(mx, s[d2]);
            float wsum = 0.f;
#pragma unroll
            for (int d2 = 0; d2 < 8; ++d2) { w[d2][i] = __expf(s[d2] - mx); wsum += w[d2][i]; }
            const float inv = 1.f / wsum;
#pragma unroll
            for (int d2 = 0; d2 < 8; ++d2) w[d2][i] *= inv;
        }
    }
    float2 simv = { simarr[0], simarr[1] };
    *reinterpret_cast<float2*>(simout + b * HWSZ + y * WW + x0) = simv;

    if (COMPUTE_NEXT) {
        // Pass 2: weighted neighbor average (reads are L1/L2 hot), same pipeline.
        float* outp = Fn + (size_t)b * IMGSZ + y * WW + x0;
        float va[3][4], vb[3][4];
        load_halo(base, ym, yp, xl, xr, va);
        for (int c = 0; c < CC; c += 2) {
            load_halo(base + (c + 1) * HWSZ, ym, yp, xl, xr, vb);
            {
                float o[2] = { 0.f, 0.f };
                acc_pass2(va, w, o);
                float2 ov = { o[0], o[1] };
                *reinterpret_cast<float2*>(outp + c * HWSZ) = ov;
            }
            if (c + 2 < CC) load_halo(base + (c + 2) * HWSZ, ym, yp, xl, xr, va);
            {
                float o[2] = { 0.f, 0.f };
                acc_pass2(vb, w, o);
                float2 ov = { o[0], o[1] };
                *reinterpret_cast<float2*>(outp + (c + 1) * HWSZ) = ov;
            }
        }
    }
}

// out[g][t][p] = 0.25 * sum_{i<4} sims[tt][4g+i][p], tt = {0,0,1,2}[t]
__global__ __launch_bounds__(256) void reduce_kernel(const float* __restrict__ sims,
                                                     float* __restrict__ out)
{
    const int idx = blockIdx.x * blockDim.x + threadIdx.x;  // 131072 float4s
    const int p4 = idx & (HWSZ / 4 - 1);
    const int t  = (idx >> 14) & 3;
    const int g  = idx >> 16;
    const int tt = (t <= 1) ? 0 : (t - 1);
    const float4* s = reinterpret_cast<const float4*>(sims) +
                      (size_t)(tt * NIMG + g * 4) * (HWSZ / 4) + p4;
    float4 a = s[0];
    float4 b = s[HWSZ / 4];
    float4 c = s[2 * (HWSZ / 4)];
    float4 d = s[3 * (HWSZ / 4)];
    float4 o;
    o.x = 0.25f * (a.x + b.x + c.x + d.x);
    o.y = 0.25f * (a.y + b.y + c.y + d.y);
    o.z = 0.25f * (a.z + b.z + c.z + d.z);
    o.w = 0.25f * (a.w + b.w + c.w + d.w);
    reinterpret_cast<float4*>(out)[idx] = o;
}

extern "C" void kernel_launch(void* const* d_in, const int* in_sizes, int n_in,
                              void* d_out, int out_size, void* d_ws, size_t ws_size,
                              hipStream_t stream)
{
    const float* F0 = (const float*)d_in[0];
    float* F1   = (float*)d_ws;                       // 8*IMGSZ floats (64 MB)
    float* F2   = F1 + (size_t)NIMG * IMGSZ;          // 64 MB
    float* sims = F2 + (size_t)NIMG * IMGSZ;          // 3 * 8 * HWSZ floats (6 MB)

    dim3 block(256);
    dim3 grid(HH / 2, NIMG);

    hipLaunchKernelGGL((step_kernel<true>),  grid, block, 0, stream, F0, F1, sims);
    hipLaunchKernelGGL((step_kernel<true>),  grid, block, 0, stream, F1, F2, sims + (size_t)NIMG * HWSZ);
    hipLaunchKernelGGL((step_kernel<false>), grid, block, 0, stream, F2, nullptr, sims + (size_t)2 * NIMG * HWSZ);

    hipLaunchKernelGGL(reduce_kernel, dim3((2 * 4 * HWSZ / 4) / 256), block, 0, stream,
                       sims, (float*)d_out);
}